// Round 1
// baseline (2089.722 us; speedup 1.0000x reference)
//
#include <hip/hip_runtime.h>
#include <math.h>

#define NN 50000      // nodes
#define GG 100        // graphs
#define NPGc 500      // nodes per graph
#define HH 256        // hidden
#define IND 128       // input dim
#define KK 3          // knn k

// ---------------------------------------------------------------------------
// Generic fp32 GEMM: C[M x 256] = A[M x K] @ B[K x 256] (+bias) (+gate epilogue)
// A2: second A source for K=512 (gate: k<256 from A, k>=256 from A2).
// mode 0: C = acc (+bias). mode 1: gate-combine epilogue.
// ---------------------------------------------------------------------------
__global__ __launch_bounds__(256)
void gemm_f32(const float* __restrict__ A, const float* __restrict__ A2,
              const float* __restrict__ B, const float* __restrict__ bias,
              float* __restrict__ C, int M, int K, int lda, int mode,
              const float* __restrict__ hn, const float* __restrict__ fn,
              const float* __restrict__ prev)
{
    __shared__ float As[16][64];
    __shared__ float Bs[16][64];
    const int tid = threadIdx.x;
    const int tr = tid >> 4, tc = tid & 15;
    const int row0 = blockIdx.x * 64, col0 = blockIdx.y * 64;
    const int ar = tid >> 2, ac = (tid & 3) * 4;   // A-tile loader coords
    const int br = tid >> 4, bc = (tid & 15) * 4;  // B-tile loader coords
    float acc[4][4] = {};
    for (int k0 = 0; k0 < K; k0 += 16) {
        const float* Asrc = A; int kof = k0;
        if (A2 != nullptr && k0 >= 256) { Asrc = A2; kof = k0 - 256; }
        int arow = row0 + ar;
        float4 av = make_float4(0.f, 0.f, 0.f, 0.f);
        if (arow < M) av = *reinterpret_cast<const float4*>(&Asrc[(size_t)arow * lda + kof + ac]);
        As[ac + 0][ar] = av.x; As[ac + 1][ar] = av.y; As[ac + 2][ar] = av.z; As[ac + 3][ar] = av.w;
        float4 bv = *reinterpret_cast<const float4*>(&B[(size_t)(k0 + br) * HH + col0 + bc]);
        *reinterpret_cast<float4*>(&Bs[br][bc]) = bv;
        __syncthreads();
        #pragma unroll
        for (int kk = 0; kk < 16; ++kk) {
            float a[4], b[4];
            #pragma unroll
            for (int i = 0; i < 4; ++i) a[i] = As[kk][tr * 4 + i];
            #pragma unroll
            for (int j = 0; j < 4; ++j) b[j] = Bs[kk][tc * 4 + j];
            #pragma unroll
            for (int i = 0; i < 4; ++i)
                #pragma unroll
                for (int j = 0; j < 4; ++j) acc[i][j] = fmaf(a[i], b[j], acc[i][j]);
        }
        __syncthreads();
    }
    const int cb = col0 + tc * 4;
    if (mode == 0) {
        float b0 = 0.f, b1 = 0.f, b2 = 0.f, b3 = 0.f;
        if (bias) { b0 = bias[cb]; b1 = bias[cb + 1]; b2 = bias[cb + 2]; b3 = bias[cb + 3]; }
        #pragma unroll
        for (int i = 0; i < 4; ++i) {
            int r = row0 + tr * 4 + i;
            if (r < M) {
                float4 v = make_float4(acc[i][0] + b0, acc[i][1] + b1, acc[i][2] + b2, acc[i][3] + b3);
                *reinterpret_cast<float4*>(&C[(size_t)r * HH + cb]) = v;
            }
        }
    } else {
        float gb[4] = { bias[cb], bias[cb + 1], bias[cb + 2], bias[cb + 3] };
        #pragma unroll
        for (int i = 0; i < 4; ++i) {
            int r = row0 + tr * 4 + i;
            if (r < M) {
                size_t o = (size_t)r * HH + cb;
                float4 hv = *reinterpret_cast<const float4*>(&hn[o]);
                float4 fv = *reinterpret_cast<const float4*>(&fn[o]);
                float4 pv = *reinterpret_cast<const float4*>(&prev[o]);
                float hvs[4] = { hv.x, hv.y, hv.z, hv.w };
                float fvs[4] = { fv.x, fv.y, fv.z, fv.w };
                float pvs[4] = { pv.x, pv.y, pv.z, pv.w };
                float ov[4];
                #pragma unroll
                for (int j = 0; j < 4; ++j) {
                    float z = acc[i][j] + gb[j];
                    float s = 1.f / (1.f + expf(-z));
                    ov[j] = s * hvs[j] + (1.f - s) * fvs[j] + pvs[j];
                }
                *reinterpret_cast<float4*>(&C[o]) = make_float4(ov[0], ov[1], ov[2], ov[3]);
            }
        }
    }
}

// ---------------------------------------------------------------------------
// Per-graph cosine-sim matrix: sim[g][i][j] = dot(xn[g,i], xn[g,j])
// ---------------------------------------------------------------------------
__global__ __launch_bounds__(256)
void sim_kernel(const float* __restrict__ xn, float* __restrict__ sim)
{
    const int g = blockIdx.z;
    const float* X = xn + (size_t)g * NPGc * HH;
    float* S = sim + (size_t)g * NPGc * NPGc;
    __shared__ float As[16][64];
    __shared__ float Bs[16][64];
    const int tid = threadIdx.x;
    const int tr = tid >> 4, tc = tid & 15;
    const int row0 = blockIdx.x * 64, col0 = blockIdx.y * 64;
    const int ar = tid >> 2, ac = (tid & 3) * 4;
    float acc[4][4] = {};
    for (int k0 = 0; k0 < HH; k0 += 16) {
        int ra = row0 + ar;
        float4 av = (ra < NPGc) ? *reinterpret_cast<const float4*>(&X[(size_t)ra * HH + k0 + ac])
                                : make_float4(0.f, 0.f, 0.f, 0.f);
        As[ac + 0][ar] = av.x; As[ac + 1][ar] = av.y; As[ac + 2][ar] = av.z; As[ac + 3][ar] = av.w;
        int rb = col0 + ar;
        float4 bv = (rb < NPGc) ? *reinterpret_cast<const float4*>(&X[(size_t)rb * HH + k0 + ac])
                                : make_float4(0.f, 0.f, 0.f, 0.f);
        Bs[ac + 0][ar] = bv.x; Bs[ac + 1][ar] = bv.y; Bs[ac + 2][ar] = bv.z; Bs[ac + 3][ar] = bv.w;
        __syncthreads();
        #pragma unroll
        for (int kk = 0; kk < 16; ++kk) {
            float a[4], b[4];
            #pragma unroll
            for (int i = 0; i < 4; ++i) a[i] = As[kk][tr * 4 + i];
            #pragma unroll
            for (int j = 0; j < 4; ++j) b[j] = Bs[kk][tc * 4 + j];
            #pragma unroll
            for (int i = 0; i < 4; ++i)
                #pragma unroll
                for (int j = 0; j < 4; ++j) acc[i][j] = fmaf(a[i], b[j], acc[i][j]);
        }
        __syncthreads();
    }
    #pragma unroll
    for (int i = 0; i < 4; ++i) {
        int r = row0 + tr * 4 + i;
        if (r < NPGc) {
            #pragma unroll
            for (int j = 0; j < 4; ++j) {
                int c = col0 + tc * 4 + j;
                if (c < NPGc) S[(size_t)r * NPGc + c] = acc[i][j];
            }
        }
    }
}

// ---------------------------------------------------------------------------
// Row L2-normalize: xn = h / (||h|| + 1e-12), one block per node
// ---------------------------------------------------------------------------
__global__ __launch_bounds__(256)
void row_normalize(const float* __restrict__ h, float* __restrict__ xn)
{
    int n = blockIdx.x, c = threadIdx.x;
    float v = h[(size_t)n * HH + c];
    __shared__ float red[256];
    red[c] = v * v;
    __syncthreads();
    for (int s = 128; s > 0; s >>= 1) {
        if (c < s) red[c] += red[c + s];
        __syncthreads();
    }
    float norm = sqrtf(red[0]);
    xn[(size_t)n * HH + c] = v / (norm + 1e-12f);
}

// ---------------------------------------------------------------------------
// Top-3 per sim row -> fsrc (global node indices). One wave per row.
// ---------------------------------------------------------------------------
__device__ __forceinline__ bool tk_better(float va, int ia, float vb, int ib)
{
    return (va > vb) || (va == vb && ia < ib);
}

__global__ __launch_bounds__(256)
void topk_kernel(const float* __restrict__ sim, int* __restrict__ fsrc)
{
    int row = blockIdx.x * 4 + (threadIdx.x >> 6);
    if (row >= NN) return;
    int lane = threadIdx.x & 63;
    int g = row / NPGc, i = row % NPGc;
    const float* srow = sim + (size_t)g * NPGc * NPGc + (size_t)i * NPGc;
    float v0 = -2.f, v1 = -2.f, v2 = -2.f;
    int i0 = 0x7fffffff, i1 = 0x7fffffff, i2 = 0x7fffffff;
    for (int j = lane; j < NPGc; j += 64) {
        float v = srow[j];
        if (tk_better(v, j, v0, i0))      { v2 = v1; i2 = i1; v1 = v0; i1 = i0; v0 = v; i0 = j; }
        else if (tk_better(v, j, v1, i1)) { v2 = v1; i2 = i1; v1 = v;  i1 = j; }
        else if (tk_better(v, j, v2, i2)) { v2 = v;  i2 = j; }
    }
    for (int off = 32; off; off >>= 1) {
        float w0 = __shfl_xor(v0, off), w1 = __shfl_xor(v1, off), w2 = __shfl_xor(v2, off);
        int   j0 = __shfl_xor(i0, off), j1 = __shfl_xor(i1, off), j2 = __shfl_xor(i2, off);
        float avv[3] = { v0, v1, v2 }, bvv[3] = { w0, w1, w2 };
        int   aii[3] = { i0, i1, i2 }, bii[3] = { j0, j1, j2 };
        float rv[3]; int ri[3];
        int p = 0, q = 0;
        #pragma unroll
        for (int t = 0; t < 3; ++t) {
            bool takeA = tk_better(avv[p], aii[p], bvv[q], bii[q]);
            rv[t] = takeA ? avv[p] : bvv[q];
            ri[t] = takeA ? aii[p] : bii[q];
            if (takeA) ++p; else ++q;
        }
        v0 = rv[0]; v1 = rv[1]; v2 = rv[2];
        i0 = ri[0]; i1 = ri[1]; i2 = ri[2];
    }
    if (lane == 0) {
        int base = g * NPGc;
        fsrc[row * 3 + 0] = base + i0;
        fsrc[row * 3 + 1] = base + i1;
        fsrc[row * 3 + 2] = base + i2;
    }
}

// ---------------------------------------------------------------------------
// CSR build
// ---------------------------------------------------------------------------
__global__ void hist_kernel(const int* __restrict__ dst, int* __restrict__ cnt, int nE)
{
    int e = blockIdx.x * 256 + threadIdx.x;
    if (e < nE) atomicAdd(&cnt[dst[e]], 1);
}

__global__ void scan1_kernel(const int* __restrict__ in, int* __restrict__ out,
                             int* __restrict__ bsum, int n)
{
    __shared__ int sh[256];
    int t = threadIdx.x;
    int i = blockIdx.x * 256 + t;
    int v = (i < n) ? in[i] : 0;
    sh[t] = v;
    __syncthreads();
    for (int s = 1; s < 256; s <<= 1) {
        int tv = (t >= s) ? sh[t - s] : 0;
        __syncthreads();
        sh[t] += tv;
        __syncthreads();
    }
    if (i < n) out[i] = sh[t] - v;  // exclusive
    if (t == 255) bsum[blockIdx.x] = sh[255];
}

__global__ void scan2_kernel(int* __restrict__ bsum, int nb)
{
    __shared__ int sh[256];
    int t = threadIdx.x;
    int v = (t < nb) ? bsum[t] : 0;
    sh[t] = v;
    __syncthreads();
    for (int s = 1; s < 256; s <<= 1) {
        int tv = (t >= s) ? sh[t - s] : 0;
        __syncthreads();
        sh[t] += tv;
        __syncthreads();
    }
    if (t < nb) bsum[t] = sh[t] - v;  // exclusive block offsets
}

__global__ void scan3_kernel(int* __restrict__ out, const int* __restrict__ bsum, int n)
{
    int i = blockIdx.x * 256 + threadIdx.x;
    if (i < n) out[i] += bsum[blockIdx.x];
}

__global__ void fill_kernel(const int* __restrict__ src, const int* __restrict__ dst,
                            const int* __restrict__ row_ptr, int* __restrict__ cursor,
                            int* __restrict__ sorted_src, int nE)
{
    int e = blockIdx.x * 256 + threadIdx.x;
    if (e < nE) {
        int d = dst[e];
        int pos = row_ptr[d] + atomicAdd(&cursor[d], 1);
        sorted_src[pos] = src[e];
    }
}

__global__ void dinv_kernel(const int* __restrict__ cnt, float* __restrict__ dinv, int n)
{
    int i = blockIdx.x * 256 + threadIdx.x;
    if (i < n) dinv[i] = rsqrtf((float)cnt[i] + 1.0f);
}

// ---------------------------------------------------------------------------
// GCN gather: out[n] = dinv[n]*(m[n]*dinv[n] + sum_e m[src_e]*dinv[src_e]) + b
// ---------------------------------------------------------------------------
__global__ __launch_bounds__(256)
void gcn_gather(const float* __restrict__ m, const int* __restrict__ row_ptr,
                const int* __restrict__ cnt, const int* __restrict__ srcs,
                const float* __restrict__ dinv, const float* __restrict__ bias,
                float* __restrict__ out)
{
    int n = blockIdx.x, c = threadIdx.x;
    float dn = dinv[n];
    float acc = m[(size_t)n * HH + c] * dn;
    int s0 = row_ptr[n], e0 = s0 + cnt[n];
    for (int e = s0; e < e0; ++e) {
        int s = srcs[e];
        acc += m[(size_t)s * HH + c] * dinv[s];
    }
    out[(size_t)n * HH + c] = acc * dn + bias[c];
}

// knn-graph conv: all degrees are K+1=4 -> coef = 0.25 everywhere
__global__ __launch_bounds__(256)
void fgcn_gather(const float* __restrict__ m, const int* __restrict__ fsrc,
                 const float* __restrict__ bias, float* __restrict__ out)
{
    int n = blockIdx.x, c = threadIdx.x;
    int s0 = fsrc[n * 3], s1 = fsrc[n * 3 + 1], s2 = fsrc[n * 3 + 2];
    float acc = m[(size_t)n * HH + c] + m[(size_t)s0 * HH + c]
              + m[(size_t)s1 * HH + c] + m[(size_t)s2 * HH + c];
    out[(size_t)n * HH + c] = 0.25f * acc + bias[c];
}

// ---------------------------------------------------------------------------
// GraphNorm: stats (S1=sum x, S2=sum x^2 per graph,channel) then apply+lrelu
// ---------------------------------------------------------------------------
__global__ __launch_bounds__(256)
void norm_stats(const float* __restrict__ x, float* __restrict__ S1, float* __restrict__ S2)
{
    int g = blockIdx.x, chunk = blockIdx.y, c = threadIdx.x;
    int r0 = chunk * 63, r1 = min(r0 + 63, NPGc);
    float s1 = 0.f, s2 = 0.f;
    for (int r = r0; r < r1; ++r) {
        float v = x[((size_t)(g * NPGc + r)) * HH + c];
        s1 += v; s2 += v * v;
    }
    atomicAdd(&S1[g * HH + c], s1);
    atomicAdd(&S2[g * HH + c], s2);
}

__global__ __launch_bounds__(256)
void norm_apply(float* __restrict__ x, const float* __restrict__ S1, const float* __restrict__ S2,
                const float* __restrict__ w, const float* __restrict__ b,
                const float* __restrict__ ms)
{
    int n = blockIdx.x, c = threadIdx.x;
    int g = n / NPGc;
    size_t o = (size_t)n * HH + c;
    float v = x[o];
    float mean = S1[g * HH + c] / (float)NPGc;
    float mm = mean * ms[c];
    float var = S2[g * HH + c] / (float)NPGc - 2.f * mm * mean + mm * mm;
    float outv = w[c] * (v - mm) * rsqrtf(var + 1e-5f) + b[c];
    x[o] = outv > 0.f ? outv : 0.01f * outv;
}

// ---------------------------------------------------------------------------
// Pool: gf[g] = (sum X0 + 2*sum X1) / 500   (all_x[-1]==all_x[1] quirk)
// ---------------------------------------------------------------------------
__global__ __launch_bounds__(256)
void pool_kernel(const float* __restrict__ X0, const float* __restrict__ X1,
                 float* __restrict__ out)
{
    int g = blockIdx.x, c = threadIdx.x;
    float s0 = 0.f, s1 = 0.f;
    for (int r = 0; r < NPGc; ++r) {
        size_t o = ((size_t)(g * NPGc + r)) * HH + c;
        s0 += X0[o];
        s1 += X1[o];
    }
    out[g * HH + c] = (s0 + 2.f * s1) / (float)NPGc;
}

__global__ void sentinel_kernel(float* out, int n)
{
    int i = blockIdx.x * 256 + threadIdx.x;
    if (i < n) out[i] = 12345.0f;
}

// ---------------------------------------------------------------------------
extern "C" void kernel_launch(void* const* d_in, const int* in_sizes, int n_in,
                              void* d_out, int out_size, void* d_ws, size_t ws_size,
                              hipStream_t stream)
{
    const float* x       = (const float*)d_in[0];
    const int* edge_idx  = (const int*)d_in[1];
    const float* emb_W   = (const float*)d_in[3];
    const float* emb_b   = (const float*)d_in[4];
    const float* conv_W  = (const float*)d_in[5];
    const float* conv_b  = (const float*)d_in[6];
    const float* fconv_W = (const float*)d_in[7];
    const float* fconv_b = (const float*)d_in[8];
    const float* norm_w  = (const float*)d_in[9];
    const float* norm_b  = (const float*)d_in[10];
    const float* norm_ms = (const float*)d_in[11];
    const float* fnorm_w = (const float*)d_in[12];
    const float* fnorm_b = (const float*)d_in[13];
    const float* fnorm_ms= (const float*)d_in[14];
    const float* gate_W  = (const float*)d_in[15];
    const float* gate_b  = (const float*)d_in[16];

    const int E = in_sizes[1] / 2;
    const int* esrc = edge_idx;
    const int* edst = edge_idx + E;

    const size_t NHf = (size_t)NN * HH;           // 12.8M floats
    char* p = (char*)d_ws;
    auto alloc = [&](size_t bytes) { char* r = p; p += (bytes + 255) & ~(size_t)255; return r; };
    float* B0 = (float*)alloc(NHf * 4);
    float* B1 = (float*)alloc(NHf * 4);
    float* B2 = (float*)alloc(NHf * 4);
    float* B3 = (float*)alloc(NHf * 4);
    float* sim = B2;  // 100MB overlays B2+B3 (contiguous), dead before layers
    int* sorted_src = (int*)alloc((size_t)E * 4);
    int* row_ptr    = (int*)alloc((size_t)NN * 4);
    int* deg_cnt    = (int*)alloc((size_t)NN * 4);
    int* cursor     = (int*)alloc((size_t)NN * 4);
    float* dinv     = (float*)alloc((size_t)NN * 4);
    int* fsrc       = (int*)alloc((size_t)NN * 3 * 4);
    float* S1       = (float*)alloc((size_t)GG * HH * 4);
    float* S2       = (float*)alloc((size_t)GG * HH * 4);  // contiguous after S1
    int* bsum       = (int*)alloc(1024);
    size_t needed = (size_t)(p - (char*)d_ws);
    if (ws_size < needed) {  // diagnosable sentinel instead of OOB writes
        sentinel_kernel<<<(out_size + 255) / 256, 256, 0, stream>>>((float*)d_out, out_size);
        return;
    }

    const int nScanB = (NN + 255) / 256;  // 196

    // zero counters
    hipMemsetAsync(deg_cnt, 0, (size_t)NN * 4, stream);
    hipMemsetAsync(cursor, 0, (size_t)NN * 4, stream);

    // 1. embedding: h0 = x @ emb_W + emb_b -> B0
    dim3 ggrid((NN + 63) / 64, 4);
    gemm_f32<<<ggrid, 256, 0, stream>>>(x, nullptr, emb_W, emb_b, B0, NN, IND, IND, 0,
                                        nullptr, nullptr, nullptr);

    // 2. CSR of edge_index by dst
    hist_kernel<<<(E + 255) / 256, 256, 0, stream>>>(edst, deg_cnt, E);
    scan1_kernel<<<nScanB, 256, 0, stream>>>(deg_cnt, row_ptr, bsum, NN);
    scan2_kernel<<<1, 256, 0, stream>>>(bsum, nScanB);
    scan3_kernel<<<nScanB, 256, 0, stream>>>(row_ptr, bsum, NN);
    fill_kernel<<<(E + 255) / 256, 256, 0, stream>>>(esrc, edst, row_ptr, cursor, sorted_src, E);
    dinv_kernel<<<(NN + 255) / 256, 256, 0, stream>>>(deg_cnt, dinv, NN);

    // 3. knn graph from h0
    row_normalize<<<NN, 256, 0, stream>>>(B0, B1);
    dim3 sgrid(8, 8, GG);
    sim_kernel<<<sgrid, 256, 0, stream>>>(B1, sim);
    topk_kernel<<<(NN + 3) / 4, 256, 0, stream>>>(sim, fsrc);

    // 4. layers
    float* h  = B0;
    float* mb = B1;
    dim3 ngrid(GG, 8);
    for (int i = 0; i < 2; ++i) {
        const float* Wc  = conv_W  + (size_t)i * HH * HH;
        const float* bc  = conv_b  + (size_t)i * HH;
        const float* Wf  = fconv_W + (size_t)i * HH * HH;
        const float* bf  = fconv_b + (size_t)i * HH;
        // h-road conv
        gemm_f32<<<ggrid, 256, 0, stream>>>(h, nullptr, Wc, nullptr, mb, NN, HH, HH, 0,
                                            nullptr, nullptr, nullptr);
        gcn_gather<<<NN, 256, 0, stream>>>(mb, row_ptr, deg_cnt, sorted_src, dinv, bc, B2);
        hipMemsetAsync(S1, 0, (size_t)2 * GG * HH * 4, stream);
        norm_stats<<<ngrid, 256, 0, stream>>>(B2, S1, S2);
        norm_apply<<<NN, 256, 0, stream>>>(B2, S1, S2, norm_w + i * HH, norm_b + i * HH,
                                           norm_ms + i * HH);
        // f-road conv (knn graph)
        gemm_f32<<<ggrid, 256, 0, stream>>>(B2, nullptr, Wf, nullptr, mb, NN, HH, HH, 0,
                                            nullptr, nullptr, nullptr);
        fgcn_gather<<<NN, 256, 0, stream>>>(mb, fsrc, bf, B3);
        hipMemsetAsync(S1, 0, (size_t)2 * GG * HH * 4, stream);
        norm_stats<<<ngrid, 256, 0, stream>>>(B3, S1, S2);
        norm_apply<<<NN, 256, 0, stream>>>(B3, S1, S2, fnorm_w + i * HH, fnorm_b + i * HH,
                                           fnorm_ms + i * HH);
        // gate + combine: h_next = sig(.)*hn + (1-sig)*fn + prev  -> mb
        gemm_f32<<<ggrid, 256, 0, stream>>>(B2, B3, gate_W, gate_b, mb, NN, 2 * HH, HH, 1,
                                            B2, B3, h);
        float* t = h; h = mb; mb = t;
    }
    // h = all_x[1], mb = all_x[0]
    pool_kernel<<<GG, 256, 0, stream>>>(mb, h, (float*)d_out);
}

// Round 2
// 1409.072 us; speedup vs baseline: 1.4830x; 1.4830x over previous
//
#include <hip/hip_runtime.h>
#include <math.h>

#define NN 50000      // nodes
#define GG 100        // graphs
#define NPGc 500      // nodes per graph
#define HH 256        // hidden
#define IND 128       // input dim

typedef __attribute__((ext_vector_type(8))) short short8v;  // 8 bf16
typedef __attribute__((ext_vector_type(4))) float f32x4;

__device__ __forceinline__ ushort f2bf(float f) {
    union { float f; unsigned u; } v; v.f = f;
    unsigned r = (v.u + 0x7fffu + ((v.u >> 16) & 1u)) >> 16;  // RNE
    return (ushort)r;
}
__device__ __forceinline__ float bf2f(ushort h) {
    union { unsigned u; float f; } v; v.u = ((unsigned)h) << 16;
    return v.f;
}

// ---------------------------------------------------------------------------
// Weight transpose+convert: src [K][N] f32 -> dst [N][K] bf16
// ---------------------------------------------------------------------------
__global__ void wcvt(const float* __restrict__ src, ushort* __restrict__ dst, int K, int N)
{
    int i = blockIdx.x * 256 + threadIdx.x;
    if (i < K * N) {
        int n = i / K, k = i % K;
        dst[i] = f2bf(src[(size_t)k * N + n]);
    }
}

// ---------------------------------------------------------------------------
// bf16 MFMA GEMM: C[M x 256] = A[M x K](f32, cvt on stage) @ Wt[N=256][K](bf16)
// tile 128x128, BK=64, 4 waves each 64x64.
// mode 0: C = acc (+bias). mode 1: gate epilogue.
// A2: second A half for K=512 (gate concat).
// ---------------------------------------------------------------------------
__global__ __launch_bounds__(256)
void gemm_mfma(const float* __restrict__ A, const float* __restrict__ A2,
               const ushort* __restrict__ Wt, const float* __restrict__ bias,
               float* __restrict__ C, int M, int K, int lda, int mode,
               const float* __restrict__ hn, const float* __restrict__ fn,
               const float* __restrict__ prev)
{
    __shared__ ushort As[128][64];
    __shared__ ushort Bs[128][64];
    const int tid = threadIdx.x;
    const int lane = tid & 63;
    const int w = tid >> 6;
    const int wr = (w >> 1) * 64, wc = (w & 1) * 64;
    const int row0 = blockIdx.x * 128, col0 = blockIdx.y * 128;
    const int lr = lane & 15, lk = (lane >> 4) * 8;
    f32x4 acc[4][4] = {};

    for (int k0 = 0; k0 < K; k0 += 64) {
        __syncthreads();
        #pragma unroll
        for (int it = 0; it < 4; ++it) {           // stage A: 128x64, f32->bf16
            int c = it * 256 + tid;
            int row = c >> 3, col = (c & 7) * 8;
            int gr = row0 + row; if (gr > M - 1) gr = M - 1;
            const float* Ap = A; int kk = k0 + col;
            if (A2 != nullptr && kk >= 256) { Ap = A2; kk -= 256; }
            const float* s = &Ap[(size_t)gr * lda + kk];
            float4 v0 = *(const float4*)s;
            float4 v1 = *(const float4*)(s + 4);
            union { ushort u[8]; int4 q; } pk;
            pk.u[0] = f2bf(v0.x); pk.u[1] = f2bf(v0.y); pk.u[2] = f2bf(v0.z); pk.u[3] = f2bf(v0.w);
            pk.u[4] = f2bf(v1.x); pk.u[5] = f2bf(v1.y); pk.u[6] = f2bf(v1.z); pk.u[7] = f2bf(v1.w);
            *(int4*)&As[row][col] = pk.q;
        }
        #pragma unroll
        for (int it = 0; it < 4; ++it) {           // stage B: Wt rows col0..+127
            int c = it * 256 + tid;
            int n = c >> 3, k = (c & 7) * 8;
            *(int4*)&Bs[n][k] = *(const int4*)&Wt[(size_t)(col0 + n) * K + k0 + k];
        }
        __syncthreads();
        #pragma unroll
        for (int ks = 0; ks < 2; ++ks) {
            short8v av[4], bv[4];
            #pragma unroll
            for (int m = 0; m < 4; ++m) av[m] = *(const short8v*)&As[wr + m * 16 + lr][ks * 32 + lk];
            #pragma unroll
            for (int n = 0; n < 4; ++n) bv[n] = *(const short8v*)&Bs[wc + n * 16 + lr][ks * 32 + lk];
            #pragma unroll
            for (int m = 0; m < 4; ++m)
                #pragma unroll
                for (int n = 0; n < 4; ++n)
                    acc[m][n] = __builtin_amdgcn_mfma_f32_16x16x32_bf16(av[m], bv[n], acc[m][n], 0, 0, 0);
        }
    }
    const int fr = (lane >> 4) * 4;
    if (mode == 0) {
        #pragma unroll
        for (int n = 0; n < 4; ++n) {
            int col = col0 + wc + n * 16 + lr;
            float bb = bias ? bias[col] : 0.f;
            #pragma unroll
            for (int m = 0; m < 4; ++m) {
                int rbase = row0 + wr + m * 16 + fr;
                #pragma unroll
                for (int r = 0; r < 4; ++r) {
                    int row = rbase + r;
                    if (row < M) C[(size_t)row * HH + col] = acc[m][n][r] + bb;
                }
            }
        }
    } else {
        #pragma unroll
        for (int n = 0; n < 4; ++n) {
            int col = col0 + wc + n * 16 + lr;
            float gb = bias[col];
            #pragma unroll
            for (int m = 0; m < 4; ++m) {
                int rbase = row0 + wr + m * 16 + fr;
                #pragma unroll
                for (int r = 0; r < 4; ++r) {
                    int row = rbase + r;
                    if (row < M) {
                        size_t o = (size_t)row * HH + col;
                        float z = acc[m][n][r] + gb;
                        float s = 1.f / (1.f + expf(-z));
                        C[o] = s * hn[o] + (1.f - s) * fn[o] + prev[o];
                    }
                }
            }
        }
    }
}

// ---------------------------------------------------------------------------
// Per-graph cosine-sim via MFMA with hi/lo bf16 split (fp32-grade accuracy):
// sim ~= hi*hi^T + hi*lo^T + lo*hi^T
// ---------------------------------------------------------------------------
__global__ __launch_bounds__(256)
void sim_mfma(const float* __restrict__ xn, float* __restrict__ sim)
{
    __shared__ ushort Ah[128][64], Al[128][64], Bh[128][64], Bl[128][64];
    const int g = blockIdx.z;
    const float* X = xn + (size_t)g * NPGc * HH;
    float* S = sim + (size_t)g * NPGc * NPGc;
    const int tid = threadIdx.x;
    const int lane = tid & 63;
    const int w = tid >> 6;
    const int wr = (w >> 1) * 64, wc = (w & 1) * 64;
    const int row0 = blockIdx.x * 128, col0 = blockIdx.y * 128;
    const int lr = lane & 15, lk = (lane >> 4) * 8;
    f32x4 acc[4][4] = {};

    for (int k0 = 0; k0 < HH; k0 += 64) {
        __syncthreads();
        #pragma unroll
        for (int it = 0; it < 4; ++it) {
            int c = it * 256 + tid;
            int row = c >> 3, col = (c & 7) * 8;
            int gr = row0 + row; if (gr > NPGc - 1) gr = NPGc - 1;
            const float* s = &X[(size_t)gr * HH + k0 + col];
            float4 v0 = *(const float4*)s;
            float4 v1 = *(const float4*)(s + 4);
            float vv[8] = { v0.x, v0.y, v0.z, v0.w, v1.x, v1.y, v1.z, v1.w };
            union { ushort u[8]; int4 q; } ph, pl;
            #pragma unroll
            for (int j = 0; j < 8; ++j) {
                ushort h = f2bf(vv[j]);
                ph.u[j] = h;
                pl.u[j] = f2bf(vv[j] - bf2f(h));
            }
            *(int4*)&Ah[row][col] = ph.q;
            *(int4*)&Al[row][col] = pl.q;
        }
        #pragma unroll
        for (int it = 0; it < 4; ++it) {
            int c = it * 256 + tid;
            int row = c >> 3, col = (c & 7) * 8;
            int gr = col0 + row; if (gr > NPGc - 1) gr = NPGc - 1;
            const float* s = &X[(size_t)gr * HH + k0 + col];
            float4 v0 = *(const float4*)s;
            float4 v1 = *(const float4*)(s + 4);
            float vv[8] = { v0.x, v0.y, v0.z, v0.w, v1.x, v1.y, v1.z, v1.w };
            union { ushort u[8]; int4 q; } ph, pl;
            #pragma unroll
            for (int j = 0; j < 8; ++j) {
                ushort h = f2bf(vv[j]);
                ph.u[j] = h;
                pl.u[j] = f2bf(vv[j] - bf2f(h));
            }
            *(int4*)&Bh[row][col] = ph.q;
            *(int4*)&Bl[row][col] = pl.q;
        }
        __syncthreads();
        #pragma unroll
        for (int ks = 0; ks < 2; ++ks) {
            short8v ah[4], al[4], bh[4], bl[4];
            #pragma unroll
            for (int m = 0; m < 4; ++m) {
                ah[m] = *(const short8v*)&Ah[wr + m * 16 + lr][ks * 32 + lk];
                al[m] = *(const short8v*)&Al[wr + m * 16 + lr][ks * 32 + lk];
            }
            #pragma unroll
            for (int n = 0; n < 4; ++n) {
                bh[n] = *(const short8v*)&Bh[wc + n * 16 + lr][ks * 32 + lk];
                bl[n] = *(const short8v*)&Bl[wc + n * 16 + lr][ks * 32 + lk];
            }
            #pragma unroll
            for (int m = 0; m < 4; ++m)
                #pragma unroll
                for (int n = 0; n < 4; ++n) {
                    acc[m][n] = __builtin_amdgcn_mfma_f32_16x16x32_bf16(ah[m], bh[n], acc[m][n], 0, 0, 0);
                    acc[m][n] = __builtin_amdgcn_mfma_f32_16x16x32_bf16(ah[m], bl[n], acc[m][n], 0, 0, 0);
                    acc[m][n] = __builtin_amdgcn_mfma_f32_16x16x32_bf16(al[m], bh[n], acc[m][n], 0, 0, 0);
                }
        }
    }
    const int fr = (lane >> 4) * 4;
    #pragma unroll
    for (int n = 0; n < 4; ++n) {
        int col = col0 + wc + n * 16 + lr;
        if (col >= NPGc) continue;
        #pragma unroll
        for (int m = 0; m < 4; ++m) {
            int rbase = row0 + wr + m * 16 + fr;
            #pragma unroll
            for (int r = 0; r < 4; ++r) {
                int row = rbase + r;
                if (row < NPGc) S[(size_t)row * NPGc + col] = acc[m][n][r];
            }
        }
    }
}

// ---------------------------------------------------------------------------
// Row L2-normalize: xn = h / (||h|| + 1e-12), one block per node
// ---------------------------------------------------------------------------
__global__ __launch_bounds__(256)
void row_normalize(const float* __restrict__ h, float* __restrict__ xn)
{
    int n = blockIdx.x, c = threadIdx.x;
    float v = h[(size_t)n * HH + c];
    __shared__ float red[256];
    red[c] = v * v;
    __syncthreads();
    for (int s = 128; s > 0; s >>= 1) {
        if (c < s) red[c] += red[c + s];
        __syncthreads();
    }
    float norm = sqrtf(red[0]);
    xn[(size_t)n * HH + c] = v / (norm + 1e-12f);
}

// ---------------------------------------------------------------------------
// Top-3 per sim row -> fsrc (global node indices). One wave per row.
// ---------------------------------------------------------------------------
__device__ __forceinline__ bool tk_better(float va, int ia, float vb, int ib)
{
    return (va > vb) || (va == vb && ia < ib);
}

__global__ __launch_bounds__(256)
void topk_kernel(const float* __restrict__ sim, int* __restrict__ fsrc)
{
    int row = blockIdx.x * 4 + (threadIdx.x >> 6);
    if (row >= NN) return;
    int lane = threadIdx.x & 63;
    int g = row / NPGc, i = row % NPGc;
    const float* srow = sim + (size_t)g * NPGc * NPGc + (size_t)i * NPGc;
    float v0 = -2.f, v1 = -2.f, v2 = -2.f;
    int i0 = 0x7fffffff, i1 = 0x7fffffff, i2 = 0x7fffffff;
    for (int j = lane; j < NPGc; j += 64) {
        float v = srow[j];
        if (tk_better(v, j, v0, i0))      { v2 = v1; i2 = i1; v1 = v0; i1 = i0; v0 = v; i0 = j; }
        else if (tk_better(v, j, v1, i1)) { v2 = v1; i2 = i1; v1 = v;  i1 = j; }
        else if (tk_better(v, j, v2, i2)) { v2 = v;  i2 = j; }
    }
    for (int off = 32; off; off >>= 1) {
        float w0 = __shfl_xor(v0, off), w1 = __shfl_xor(v1, off), w2 = __shfl_xor(v2, off);
        int   j0 = __shfl_xor(i0, off), j1 = __shfl_xor(i1, off), j2 = __shfl_xor(i2, off);
        float avv[3] = { v0, v1, v2 }, bvv[3] = { w0, w1, w2 };
        int   aii[3] = { i0, i1, i2 }, bii[3] = { j0, j1, j2 };
        float rv[3]; int ri[3];
        int p = 0, q = 0;
        #pragma unroll
        for (int t = 0; t < 3; ++t) {
            bool takeA = tk_better(avv[p], aii[p], bvv[q], bii[q]);
            rv[t] = takeA ? avv[p] : bvv[q];
            ri[t] = takeA ? aii[p] : bii[q];
            if (takeA) ++p; else ++q;
        }
        v0 = rv[0]; v1 = rv[1]; v2 = rv[2];
        i0 = ri[0]; i1 = ri[1]; i2 = ri[2];
    }
    if (lane == 0) {
        int base = g * NPGc;
        fsrc[row * 3 + 0] = base + i0;
        fsrc[row * 3 + 1] = base + i1;
        fsrc[row * 3 + 2] = base + i2;
    }
}

// ---------------------------------------------------------------------------
// CSR build
// ---------------------------------------------------------------------------
__global__ void hist_kernel(const int* __restrict__ dst, int* __restrict__ cnt, int nE)
{
    int e = blockIdx.x * 256 + threadIdx.x;
    if (e < nE) atomicAdd(&cnt[dst[e]], 1);
}

__global__ void scan1_kernel(const int* __restrict__ in, int* __restrict__ out,
                             int* __restrict__ bsum, int n)
{
    __shared__ int sh[256];
    int t = threadIdx.x;
    int i = blockIdx.x * 256 + t;
    int v = (i < n) ? in[i] : 0;
    sh[t] = v;
    __syncthreads();
    for (int s = 1; s < 256; s <<= 1) {
        int tv = (t >= s) ? sh[t - s] : 0;
        __syncthreads();
        sh[t] += tv;
        __syncthreads();
    }
    if (i < n) out[i] = sh[t] - v;  // exclusive
    if (t == 255) bsum[blockIdx.x] = sh[255];
}

__global__ void scan2_kernel(int* __restrict__ bsum, int nb)
{
    __shared__ int sh[256];
    int t = threadIdx.x;
    int v = (t < nb) ? bsum[t] : 0;
    sh[t] = v;
    __syncthreads();
    for (int s = 1; s < 256; s <<= 1) {
        int tv = (t >= s) ? sh[t - s] : 0;
        __syncthreads();
        sh[t] += tv;
        __syncthreads();
    }
    if (t < nb) bsum[t] = sh[t] - v;  // exclusive block offsets
}

__global__ void scan3_kernel(int* __restrict__ out, const int* __restrict__ bsum, int n)
{
    int i = blockIdx.x * 256 + threadIdx.x;
    if (i < n) out[i] += bsum[blockIdx.x];
}

__global__ void fill_kernel(const int* __restrict__ src, const int* __restrict__ dst,
                            const int* __restrict__ row_ptr, int* __restrict__ cursor,
                            int* __restrict__ sorted_src, int nE)
{
    int e = blockIdx.x * 256 + threadIdx.x;
    if (e < nE) {
        int d = dst[e];
        int pos = row_ptr[d] + atomicAdd(&cursor[d], 1);
        sorted_src[pos] = src[e];
    }
}

__global__ void dinv_kernel(const int* __restrict__ cnt, float* __restrict__ dinv, int n)
{
    int i = blockIdx.x * 256 + threadIdx.x;
    if (i < n) dinv[i] = rsqrtf((float)cnt[i] + 1.0f);
}

// ---------------------------------------------------------------------------
// GCN gather
// ---------------------------------------------------------------------------
__global__ __launch_bounds__(256)
void gcn_gather(const float* __restrict__ m, const int* __restrict__ row_ptr,
                const int* __restrict__ cnt, const int* __restrict__ srcs,
                const float* __restrict__ dinv, const float* __restrict__ bias,
                float* __restrict__ out)
{
    int n = blockIdx.x, c = threadIdx.x;
    float dn = dinv[n];
    float acc = m[(size_t)n * HH + c] * dn;
    int s0 = row_ptr[n], e0 = s0 + cnt[n];
    for (int e = s0; e < e0; ++e) {
        int s = srcs[e];
        acc += m[(size_t)s * HH + c] * dinv[s];
    }
    out[(size_t)n * HH + c] = acc * dn + bias[c];
}

// knn-graph conv: all degrees are K+1=4 -> coef = 0.25 everywhere
__global__ __launch_bounds__(256)
void fgcn_gather(const float* __restrict__ m, const int* __restrict__ fsrc,
                 const float* __restrict__ bias, float* __restrict__ out)
{
    int n = blockIdx.x, c = threadIdx.x;
    int s0 = fsrc[n * 3], s1 = fsrc[n * 3 + 1], s2 = fsrc[n * 3 + 2];
    float acc = m[(size_t)n * HH + c] + m[(size_t)s0 * HH + c]
              + m[(size_t)s1 * HH + c] + m[(size_t)s2 * HH + c];
    out[(size_t)n * HH + c] = 0.25f * acc + bias[c];
}

// ---------------------------------------------------------------------------
// GraphNorm
// ---------------------------------------------------------------------------
__global__ __launch_bounds__(256)
void norm_stats(const float* __restrict__ x, float* __restrict__ S1, float* __restrict__ S2)
{
    int g = blockIdx.x, chunk = blockIdx.y, c = threadIdx.x;
    int r0 = chunk * 63, r1 = min(r0 + 63, NPGc);
    float s1 = 0.f, s2 = 0.f;
    for (int r = r0; r < r1; ++r) {
        float v = x[((size_t)(g * NPGc + r)) * HH + c];
        s1 += v; s2 += v * v;
    }
    atomicAdd(&S1[g * HH + c], s1);
    atomicAdd(&S2[g * HH + c], s2);
}

__global__ __launch_bounds__(256)
void norm_apply(float* __restrict__ x, const float* __restrict__ S1, const float* __restrict__ S2,
                const float* __restrict__ w, const float* __restrict__ b,
                const float* __restrict__ ms)
{
    int n = blockIdx.x, c = threadIdx.x;
    int g = n / NPGc;
    size_t o = (size_t)n * HH + c;
    float v = x[o];
    float mean = S1[g * HH + c] / (float)NPGc;
    float mm = mean * ms[c];
    float var = S2[g * HH + c] / (float)NPGc - 2.f * mm * mean + mm * mm;
    float outv = w[c] * (v - mm) * rsqrtf(var + 1e-5f) + b[c];
    x[o] = outv > 0.f ? outv : 0.01f * outv;
}

// ---------------------------------------------------------------------------
// Pool: gf[g] = (sum X0 + 2*sum X1) / 500   (all_x[-1]==all_x[1] quirk)
// ---------------------------------------------------------------------------
__global__ __launch_bounds__(256)
void pool_kernel(const float* __restrict__ X0, const float* __restrict__ X1,
                 float* __restrict__ out)
{
    int g = blockIdx.x, c = threadIdx.x;
    float s0 = 0.f, s1 = 0.f;
    for (int r = 0; r < NPGc; ++r) {
        size_t o = ((size_t)(g * NPGc + r)) * HH + c;
        s0 += X0[o];
        s1 += X1[o];
    }
    out[g * HH + c] = (s0 + 2.f * s1) / (float)NPGc;
}

__global__ void sentinel_kernel(float* out, int n)
{
    int i = blockIdx.x * 256 + threadIdx.x;
    if (i < n) out[i] = 12345.0f;
}

// ---------------------------------------------------------------------------
extern "C" void kernel_launch(void* const* d_in, const int* in_sizes, int n_in,
                              void* d_out, int out_size, void* d_ws, size_t ws_size,
                              hipStream_t stream)
{
    const float* x       = (const float*)d_in[0];
    const int* edge_idx  = (const int*)d_in[1];
    const float* emb_W   = (const float*)d_in[3];
    const float* emb_b   = (const float*)d_in[4];
    const float* conv_W  = (const float*)d_in[5];
    const float* conv_b  = (const float*)d_in[6];
    const float* fconv_W = (const float*)d_in[7];
    const float* fconv_b = (const float*)d_in[8];
    const float* norm_w  = (const float*)d_in[9];
    const float* norm_b  = (const float*)d_in[10];
    const float* norm_ms = (const float*)d_in[11];
    const float* fnorm_w = (const float*)d_in[12];
    const float* fnorm_b = (const float*)d_in[13];
    const float* fnorm_ms= (const float*)d_in[14];
    const float* gate_W  = (const float*)d_in[15];
    const float* gate_b  = (const float*)d_in[16];

    const int E = in_sizes[1] / 2;
    const int* esrc = edge_idx;
    const int* edst = edge_idx + E;

    const size_t NHf = (size_t)NN * HH;           // 12.8M floats
    char* p = (char*)d_ws;
    auto alloc = [&](size_t bytes) { char* r = p; p += (bytes + 255) & ~(size_t)255; return r; };
    float* B0 = (float*)alloc(NHf * 4);
    float* B1 = (float*)alloc(NHf * 4);
    float* B2 = (float*)alloc(NHf * 4);
    float* B3 = (float*)alloc(NHf * 4);
    float* sim = B2;  // 100MB overlays B2+B3 (contiguous), dead before layers
    int* sorted_src = (int*)alloc((size_t)E * 4);
    int* row_ptr    = (int*)alloc((size_t)NN * 4);
    int* deg_cnt    = (int*)alloc((size_t)NN * 4);
    int* cursor     = (int*)alloc((size_t)NN * 4);
    float* dinv     = (float*)alloc((size_t)NN * 4);
    int* fsrc       = (int*)alloc((size_t)NN * 3 * 4);
    float* S1       = (float*)alloc((size_t)GG * HH * 4);
    float* S2       = (float*)alloc((size_t)GG * HH * 4);  // contiguous after S1
    int* bsum       = (int*)alloc(1024);
    ushort* wts     = (ushort*)alloc((size_t)425984 * 2);  // all W^T bf16
    size_t needed = (size_t)(p - (char*)d_ws);
    if (ws_size < needed) {
        sentinel_kernel<<<(out_size + 255) / 256, 256, 0, stream>>>((float*)d_out, out_size);
        return;
    }
    ushort* embWt  = wts;                     // [256][128]
    ushort* convWt0 = wts + 32768;            // [256][256]
    ushort* convWt1 = wts + 32768 + 65536;
    ushort* fconvWt0 = wts + 163840;
    ushort* fconvWt1 = wts + 163840 + 65536;
    ushort* gateWt  = wts + 294912;           // [256][512]

    const int nScanB = (NN + 255) / 256;  // 196

    hipMemsetAsync(deg_cnt, 0, (size_t)NN * 4, stream);
    hipMemsetAsync(cursor, 0, (size_t)NN * 4, stream);

    // 0. weight transpose+cvt
    wcvt<<<(32768 + 255) / 256, 256, 0, stream>>>(emb_W, embWt, IND, HH);
    wcvt<<<(65536 + 255) / 256, 256, 0, stream>>>(conv_W, convWt0, HH, HH);
    wcvt<<<(65536 + 255) / 256, 256, 0, stream>>>(conv_W + 65536, convWt1, HH, HH);
    wcvt<<<(65536 + 255) / 256, 256, 0, stream>>>(fconv_W, fconvWt0, HH, HH);
    wcvt<<<(65536 + 255) / 256, 256, 0, stream>>>(fconv_W + 65536, fconvWt1, HH, HH);
    wcvt<<<(131072 + 255) / 256, 256, 0, stream>>>(gate_W, gateWt, 2 * HH, HH);

    // 1. embedding: h0 = x @ emb_W + emb_b -> B0
    dim3 ggrid((NN + 127) / 128, 2);
    gemm_mfma<<<ggrid, 256, 0, stream>>>(x, nullptr, embWt, emb_b, B0, NN, IND, IND, 0,
                                         nullptr, nullptr, nullptr);

    // 2. CSR of edge_index by dst
    hist_kernel<<<(E + 255) / 256, 256, 0, stream>>>(edst, deg_cnt, E);
    scan1_kernel<<<nScanB, 256, 0, stream>>>(deg_cnt, row_ptr, bsum, NN);
    scan2_kernel<<<1, 256, 0, stream>>>(bsum, nScanB);
    scan3_kernel<<<nScanB, 256, 0, stream>>>(row_ptr, bsum, NN);
    fill_kernel<<<(E + 255) / 256, 256, 0, stream>>>(esrc, edst, row_ptr, cursor, sorted_src, E);
    dinv_kernel<<<(NN + 255) / 256, 256, 0, stream>>>(deg_cnt, dinv, NN);

    // 3. knn graph from h0
    row_normalize<<<NN, 256, 0, stream>>>(B0, B1);
    dim3 sgrid(4, 4, GG);
    sim_mfma<<<sgrid, 256, 0, stream>>>(B1, sim);
    topk_kernel<<<(NN + 3) / 4, 256, 0, stream>>>(sim, fsrc);

    // 4. layers
    float* h  = B0;
    float* mb = B1;
    dim3 ngrid(GG, 8);
    for (int i = 0; i < 2; ++i) {
        const ushort* Wc = (i == 0) ? convWt0 : convWt1;
        const ushort* Wf = (i == 0) ? fconvWt0 : fconvWt1;
        const float* bc  = conv_b  + (size_t)i * HH;
        const float* bf  = fconv_b + (size_t)i * HH;
        // h-road conv
        gemm_mfma<<<ggrid, 256, 0, stream>>>(h, nullptr, Wc, nullptr, mb, NN, HH, HH, 0,
                                             nullptr, nullptr, nullptr);
        gcn_gather<<<NN, 256, 0, stream>>>(mb, row_ptr, deg_cnt, sorted_src, dinv, bc, B2);
        hipMemsetAsync(S1, 0, (size_t)2 * GG * HH * 4, stream);
        norm_stats<<<ngrid, 256, 0, stream>>>(B2, S1, S2);
        norm_apply<<<NN, 256, 0, stream>>>(B2, S1, S2, norm_w + i * HH, norm_b + i * HH,
                                           norm_ms + i * HH);
        // f-road conv (knn graph)
        gemm_mfma<<<ggrid, 256, 0, stream>>>(B2, nullptr, Wf, nullptr, mb, NN, HH, HH, 0,
                                             nullptr, nullptr, nullptr);
        fgcn_gather<<<NN, 256, 0, stream>>>(mb, fsrc, bf, B3);
        hipMemsetAsync(S1, 0, (size_t)2 * GG * HH * 4, stream);
        norm_stats<<<ngrid, 256, 0, stream>>>(B3, S1, S2);
        norm_apply<<<NN, 256, 0, stream>>>(B3, S1, S2, fnorm_w + i * HH, fnorm_b + i * HH,
                                           fnorm_ms + i * HH);
        // gate + combine
        gemm_mfma<<<ggrid, 256, 0, stream>>>(B2, B3, gateWt, gate_b, mb, NN, 2 * HH, HH, 1,
                                             B2, B3, h);
        float* t = h; h = mb; mb = t;
    }
    // h = all_x[1], mb = all_x[0]
    pool_kernel<<<GG, 256, 0, stream>>>(mb, h, (float*)d_out);
}